// Round 2
// baseline (348.775 us; speedup 1.0000x reference)
//
#include <hip/hip_runtime.h>
#include <hip/hip_bf16.h>

#define B_ 4
#define S_ 4
#define C_ 4
#define L_ 512
#define E_ 64
#define A_ 32
#define H_ 8
#define HA_ 256      // H_*A_
#define KREAL 2052   // S_*L_ + C_
#define KP 2112      // padded to 33*64
#define NKT 33
#define SCALE 0.17677669529663687f  // 1/sqrt(32)

using bf16  = __bf16;
using bf16x8 = __attribute__((ext_vector_type(8))) __bf16;
using f32x4  = __attribute__((ext_vector_type(4))) float;

// workspace layout (byte offsets)
#define OFF_QS    0ull            // bf16 [B][S][H][L][A]    2,097,152 elems
#define OFF_KALL  4194304ull      // bf16 [B][H][KP][A]      2,162,688 elems
#define OFF_VT    8519680ull      // bf16 [B][H][A][KP]      2,162,688 elems
#define OFF_OUTS  12845056ull     // bf16 [B][S][L][HA]      2,097,152 elems
#define OFF_OUTC  17039360ull     // f32  [B][C][HA]         4,096 elems
#define OFF_CANON 17055744ull     // bf16 canonical inputs   2,100,224 elems
#define OFF_FLAG  21256192ull     // int  is_f32 flag
// total 21,256,196 bytes

// canonical pool element offsets
#define C_XQ   0
#define C_XK   524288
#define C_XV   1048576
#define C_QC   1572864
#define C_KC   1573888
#define C_VC   1574912
#define C_WQ   1575936
#define C_WK   1641472
#define C_WV   1707008
#define C_WQC  1772544
#define C_WKC  1838080
#define C_WVC  1903616
#define C_HWS  1969152
#define C_HWC  2034688
#define C_END  2100224

// ---------------------------------------------------------------------------
// Kernel 0a: dtype detection. Inspect low halfwords of input 0: if data is
// f32, low halves of words are mantissa noise (uniform bits -> wild
// exponents); if bf16, they are sane N(0,1) values.
// ---------------------------------------------------------------------------
__global__ __launch_bounds__(256) void detect_kernel(
    const unsigned short* __restrict__ x, int* __restrict__ flag)
{
  __shared__ int cnt;
  if (threadIdx.x == 0) cnt = 0;
  __syncthreads();
  int weird = 0;
  for (int i = threadIdx.x; i < 4096; i += 256) {
    unsigned short h = x[2 * i];      // low half of 32-bit word i
    int e = (h >> 7) & 0xFF;
    if (e == 0xFF || e < 0x60 || e > 0x9F) weird++;
  }
  atomicAdd(&cnt, weird);
  __syncthreads();
  if (threadIdx.x == 0) *flag = (cnt > 1024) ? 1 : 0;   // >25% weird => f32
}

// ---------------------------------------------------------------------------
// Kernel 0b: canonicalize all float inputs to bf16 in ws.
// ---------------------------------------------------------------------------
struct ConvArgs {
  const void* src[13];
  int n[13];
  int off[13];
};

__global__ __launch_bounds__(256) void conv_kernel(
    ConvArgs args, bf16* __restrict__ dst, const int* __restrict__ flag)
{
  bool isf32 = (*flag != 0);
  int stride = gridDim.x * blockDim.x;
  int t0 = blockIdx.x * blockDim.x + threadIdx.x;
#pragma unroll 1
  for (int seg = 0; seg < 13; ++seg) {
    int n = args.n[seg];
    bf16* d = dst + args.off[seg];
    if (isf32) {
      const float* s = (const float*)args.src[seg];
      for (int i = t0; i < n; i += stride) d[i] = (bf16)s[i];
    } else {
      const bf16* s = (const bf16*)args.src[seg];
      for (int i = t0; i < n; i += stride) d[i] = s[i];
    }
  }
}

// ---------------------------------------------------------------------------
// Kernel 1: QKV projections.
// blocks 0..127:  (b,s,h) seq projections via MFMA (X 512x64 * W 64x32)
// blocks 128..255: (b,c,h) constant K/V rows + zero pad keys
// ---------------------------------------------------------------------------
__global__ __launch_bounds__(256) void proj_kernel(
    const bf16* __restrict__ canon,
    bf16* __restrict__ qs, bf16* __restrict__ kall, bf16* __restrict__ vt)
{
  const bf16* xq    = canon + C_XQ;
  const bf16* xk    = canon + C_XK;
  const bf16* xv    = canon + C_XV;
  const bf16* kc_in = canon + C_KC;
  const bf16* vc_in = canon + C_VC;
  const bf16* wq    = canon + C_WQ;
  const bf16* wk    = canon + C_WK;
  const bf16* wv    = canon + C_WV;
  const bf16* wkc   = canon + C_WKC;
  const bf16* wvc   = canon + C_WVC;
  int bid = blockIdx.x;
  int tid = threadIdx.x;
  if (bid < 128) {
    int b = bid >> 5, s = (bid >> 3) & 3, h = bid & 7;
    __shared__ bf16 wt[3 * 32 * 72];   // W^T [a][e], row stride 72
    for (int idx = tid; idx < 2048; idx += 256) {
      int e = idx >> 5, a = idx & 31;
      size_t src = ((size_t)(s * H_ + h) * E_ + e) * A_ + a;
      wt[0 * 2304 + a * 72 + e] = wq[src];
      wt[1 * 2304 + a * 72 + e] = wk[src];
      wt[2 * 2304 + a * 72 + e] = wv[src];
    }
    __syncthreads();
    int lane = tid & 63, wave = tid >> 6;
    int quad = lane >> 4, r = lane & 15;
    bf16x8 bq[2][2], bk[2][2], bv[2][2];
#pragma unroll
    for (int kc = 0; kc < 2; ++kc)
#pragma unroll
      for (int nt = 0; nt < 2; ++nt) {
        int off = (nt * 16 + r) * 72 + kc * 32 + quad * 8;
        bq[kc][nt] = *(const bf16x8*)&wt[off];
        bk[kc][nt] = *(const bf16x8*)&wt[2304 + off];
        bv[kc][nt] = *(const bf16x8*)&wt[4608 + off];
      }
    const size_t xbase = (size_t)(b * S_ + s) * L_ * E_;
    const size_t qsb   = (size_t)((b * S_ + s) * H_ + h) * L_ * A_;
    const size_t kab   = (size_t)(b * H_ + h) * KP * A_;
    const size_t vtb   = (size_t)(b * H_ + h) * A_ * KP;
#pragma unroll 1
    for (int i = 0; i < 8; ++i) {
      int row0 = (wave * 8 + i) * 16;
      size_t rowoff = xbase + (size_t)(row0 + r) * E_ + quad * 8;
      bf16x8 aq0 = *(const bf16x8*)&xq[rowoff];
      bf16x8 aq1 = *(const bf16x8*)&xq[rowoff + 32];
      bf16x8 ak0 = *(const bf16x8*)&xk[rowoff];
      bf16x8 ak1 = *(const bf16x8*)&xk[rowoff + 32];
      bf16x8 av0 = *(const bf16x8*)&xv[rowoff];
      bf16x8 av1 = *(const bf16x8*)&xv[rowoff + 32];
#pragma unroll
      for (int nt = 0; nt < 2; ++nt) {
        f32x4 accq = {0.f,0.f,0.f,0.f}, acck = {0.f,0.f,0.f,0.f}, accv = {0.f,0.f,0.f,0.f};
        accq = __builtin_amdgcn_mfma_f32_16x16x32_bf16(aq0, bq[0][nt], accq, 0,0,0);
        accq = __builtin_amdgcn_mfma_f32_16x16x32_bf16(aq1, bq[1][nt], accq, 0,0,0);
        acck = __builtin_amdgcn_mfma_f32_16x16x32_bf16(ak0, bk[0][nt], acck, 0,0,0);
        acck = __builtin_amdgcn_mfma_f32_16x16x32_bf16(ak1, bk[1][nt], acck, 0,0,0);
        accv = __builtin_amdgcn_mfma_f32_16x16x32_bf16(av0, bv[0][nt], accv, 0,0,0);
        accv = __builtin_amdgcn_mfma_f32_16x16x32_bf16(av1, bv[1][nt], accv, 0,0,0);
#pragma unroll
        for (int reg = 0; reg < 4; ++reg) {
          int l = row0 + quad * 4 + reg;     // D row = quad*4+reg
          int a = nt * 16 + r;               // D col = lane&15
          qs[qsb + (size_t)l * A_ + a]              = (bf16)accq[reg];
          kall[kab + (size_t)(s * L_ + l) * A_ + a] = (bf16)acck[reg];
          vt[vtb + (size_t)a * KP + s * L_ + l]     = (bf16)accv[reg];
        }
      }
    }
  } else {
    int cid = bid - 128;
    int b = cid >> 5, c = (cid >> 3) & 3, h = cid & 7;
    if (tid < 32) {
      int a = tid;
      float kacc = 0.f, vacc = 0.f;
#pragma unroll 8
      for (int e = 0; e < E_; ++e) {
        float xke = (float)kc_in[(b * C_ + c) * E_ + e];
        float xve = (float)vc_in[(b * C_ + c) * E_ + e];
        float wke = (float)wkc[((size_t)(c * H_ + h) * E_ + e) * A_ + a];
        float wve = (float)wvc[((size_t)(c * H_ + h) * E_ + e) * A_ + a];
        kacc += xke * wke;
        vacc += xve * wve;
      }
      kall[((size_t)(b * H_ + h) * KP + (S_ * L_ + c)) * A_ + a] = (bf16)kacc;
      vt[((size_t)(b * H_ + h) * A_ + a) * KP + (S_ * L_ + c)]   = (bf16)vacc;
    }
    if (c == 0) {  // zero pad keys 2052..2111
      for (int idx = tid; idx < 60 * 32; idx += 256) {
        int k = KREAL + (idx >> 5), a = idx & 31;
        kall[((size_t)(b * H_ + h) * KP + k) * A_ + a] = (bf16)0.f;
        vt[((size_t)(b * H_ + h) * A_ + a) * KP + k]   = (bf16)0.f;
      }
    }
  }
}

// ---------------------------------------------------------------------------
// Kernel 2: flash attention over seq queries. grid 512 = (b,s,h,qt of 128)
// ---------------------------------------------------------------------------
__global__ __launch_bounds__(256) void attn_kernel(
    const bf16* __restrict__ qs, const bf16* __restrict__ kall, const bf16* __restrict__ vt,
    const int* __restrict__ maskp, bf16* __restrict__ outs)
{
  __shared__ bf16 kt_lds[64 * 40];     // K tile  [key][a], row stride 40
  __shared__ bf16 vt_lds[32 * 72];     // V^T tile [a][key], row stride 72
  __shared__ bf16 p_lds[4 * 16 * 72];  // per-wave P tile [row][key], stride 72
  int bid = blockIdx.x, tid = threadIdx.x;
  int qt = bid & 3, h = (bid >> 2) & 7, s = (bid >> 5) & 3, b = (bid >> 7) & 3;
  int lane = tid & 63, wave = tid >> 6, quad = lane >> 4, r = lane & 15;
  bool causal = (*maskp != 0);         // any nonzero bit pattern => causal
  int wrow = qt * 128 + wave * 32;

  const size_t qsb = (size_t)((b * S_ + s) * H_ + h) * L_ * A_;
  bf16x8 aq[2];
  aq[0] = *(const bf16x8*)&qs[qsb + (size_t)(wrow + r) * A_ + quad * 8];
  aq[1] = *(const bf16x8*)&qs[qsb + (size_t)(wrow + 16 + r) * A_ + quad * 8];

  f32x4 o[2][2];
  float m_run[2][4], l_run[2][4];
#pragma unroll
  for (int rt = 0; rt < 2; ++rt) {
#pragma unroll
    for (int nt = 0; nt < 2; ++nt) { f32x4 z = {0.f,0.f,0.f,0.f}; o[rt][nt] = z; }
#pragma unroll
    for (int g = 0; g < 4; ++g) { m_run[rt][g] = -1e30f; l_run[rt][g] = 0.f; }
  }

  const size_t kbase = (size_t)(b * H_ + h) * KP * A_;
  const size_t vbase = (size_t)(b * H_ + h) * A_ * KP;
  const int pbase = wave * 16 * 72;

#pragma unroll 1
  for (int kt = 0; kt < NKT; ++kt) {
    __syncthreads();
    {
      int krow = tid >> 2, c4 = tid & 3;
      *(bf16x8*)&kt_lds[krow * 40 + c4 * 8] =
          *(const bf16x8*)&kall[kbase + (size_t)(kt * 64 + krow) * A_ + c4 * 8];
      int a8 = tid >> 3, c8 = tid & 7;
      *(bf16x8*)&vt_lds[a8 * 72 + c8 * 8] =
          *(const bf16x8*)&vt[vbase + (size_t)a8 * KP + kt * 64 + c8 * 8];
    }
    __syncthreads();
#pragma unroll
    for (int rt = 0; rt < 2; ++rt) {
      f32x4 sf[4];
#pragma unroll
      for (int kg = 0; kg < 4; ++kg) {
        bf16x8 bfr = *(const bf16x8*)&kt_lds[(kg * 16 + r) * 40 + quad * 8];
        f32x4 z = {0.f,0.f,0.f,0.f};
        sf[kg] = __builtin_amdgcn_mfma_f32_16x16x32_bf16(aq[rt], bfr, z, 0,0,0);
      }
      int rowb = wrow + rt * 16 + quad * 4;
#pragma unroll
      for (int reg = 0; reg < 4; ++reg) {
        int lrow = rowb + reg;
        float v0[4];
        float tmax = -__builtin_inff();
#pragma unroll
        for (int kg = 0; kg < 4; ++kg) {
          int kidx = kt * 64 + kg * 16 + r;
          bool vis = (kidx < KREAL) &&
                     (!causal || kidx >= S_ * L_ || (kidx & (L_ - 1)) <= lrow);
          float val = vis ? sf[kg][reg] * SCALE : -__builtin_inff();
          v0[kg] = val;
          tmax = fmaxf(tmax, val);
        }
        tmax = fmaxf(tmax, __shfl_xor(tmax, 1));
        tmax = fmaxf(tmax, __shfl_xor(tmax, 2));
        tmax = fmaxf(tmax, __shfl_xor(tmax, 4));
        tmax = fmaxf(tmax, __shfl_xor(tmax, 8));
        float mold = m_run[rt][reg];
        float mnew = fmaxf(mold, tmax);
        float alpha = __expf(mold - mnew);
        float psum = 0.f;
#pragma unroll
        for (int kg = 0; kg < 4; ++kg) {
          float p = __expf(v0[kg] - mnew);
          psum += p;
          p_lds[pbase + (quad * 4 + reg) * 72 + kg * 16 + r] = (bf16)p;
        }
        psum += __shfl_xor(psum, 1);
        psum += __shfl_xor(psum, 2);
        psum += __shfl_xor(psum, 4);
        psum += __shfl_xor(psum, 8);
        m_run[rt][reg] = mnew;
        l_run[rt][reg] = l_run[rt][reg] * alpha + psum;
        o[rt][0][reg] *= alpha;
        o[rt][1][reg] *= alpha;
      }
#pragma unroll
      for (int kc2 = 0; kc2 < 2; ++kc2) {
        bf16x8 ap = *(const bf16x8*)&p_lds[pbase + r * 72 + kc2 * 32 + quad * 8];
#pragma unroll
        for (int nt = 0; nt < 2; ++nt) {
          bf16x8 bv = *(const bf16x8*)&vt_lds[(nt * 16 + r) * 72 + kc2 * 32 + quad * 8];
          o[rt][nt] = __builtin_amdgcn_mfma_f32_16x16x32_bf16(ap, bv, o[rt][nt], 0,0,0);
        }
      }
    }
  }
  const size_t obase = (size_t)(b * S_ + s) * L_ * HA_;
#pragma unroll
  for (int rt = 0; rt < 2; ++rt)
#pragma unroll
    for (int nt = 0; nt < 2; ++nt)
#pragma unroll
      for (int reg = 0; reg < 4; ++reg) {
        int lrow = wrow + rt * 16 + quad * 4 + reg;
        int f = h * A_ + nt * 16 + r;
        outs[obase + (size_t)lrow * HA_ + f] = (bf16)(o[rt][nt][reg] / l_run[rt][reg]);
      }
}

// ---------------------------------------------------------------------------
// Kernel 3: constant-query attention (no mask). grid 128 = (b,c,h), 1 wave.
// ---------------------------------------------------------------------------
__global__ __launch_bounds__(64) void cattn_kernel(
    const bf16* __restrict__ canon,
    const bf16* __restrict__ kall, const bf16* __restrict__ vt,
    float* __restrict__ outc)
{
  const bf16* qc  = canon + C_QC;
  const bf16* wqc = canon + C_WQC;
  __shared__ float qsh[32];
  __shared__ float parr[KREAL];
  int bid = blockIdx.x, lane = threadIdx.x;
  int b = bid >> 5, c = (bid >> 3) & 3, h = bid & 7;
  if (lane < 32) {
    float acc = 0.f;
#pragma unroll 8
    for (int e = 0; e < E_; ++e)
      acc += (float)qc[(b * C_ + c) * E_ + e] *
             (float)wqc[((size_t)(c * H_ + h) * E_ + e) * A_ + lane];
    qsh[lane] = acc;
  }
  __syncthreads();
  const size_t kbase = (size_t)(b * H_ + h) * KP * A_;
  float lmax = -__builtin_inff();
#pragma unroll 1
  for (int j = 0; j < 33; ++j) {
    int k = lane + j * 64;
    if (k < KREAL) {
      float d = 0.f;
#pragma unroll
      for (int a = 0; a < A_; ++a)
        d += qsh[a] * (float)kall[kbase + (size_t)k * A_ + a];
      d *= SCALE;
      parr[k] = d;
      lmax = fmaxf(lmax, d);
    }
  }
#pragma unroll
  for (int dlt = 1; dlt < 64; dlt <<= 1) lmax = fmaxf(lmax, __shfl_xor(lmax, dlt));
  __syncthreads();
  float lsum = 0.f;
#pragma unroll 1
  for (int j = 0; j < 33; ++j) {
    int k = lane + j * 64;
    if (k < KREAL) {
      float p = __expf(parr[k] - lmax);
      parr[k] = p;
      lsum += p;
    }
  }
#pragma unroll
  for (int dlt = 1; dlt < 64; dlt <<= 1) lsum += __shfl_xor(lsum, dlt);
  __syncthreads();
  int a = lane & 31, half = lane >> 5;
  const size_t vbase = (size_t)(b * H_ + h) * A_ * KP;
  float acc = 0.f;
#pragma unroll 4
  for (int k = half; k < KREAL; k += 2)
    acc += parr[k] * (float)vt[vbase + (size_t)a * KP + k];
  acc += __shfl_xor(acc, 32);
  if (lane < 32)
    outc[(size_t)(b * C_ + c) * HA_ + h * A_ + a] = acc / lsum;
}

// ---------------------------------------------------------------------------
// Kernel 4: seq head projection out_s(512x256) * W(256x64) via MFMA.
// grid 128 = (b,s,rowchunk of 64). Dual-format store per is_f32 flag.
// ---------------------------------------------------------------------------
__global__ __launch_bounds__(256) void hproj_s_kernel(
    const bf16* __restrict__ outs, const bf16* __restrict__ canon,
    void* __restrict__ out, const int* __restrict__ flag)
{
  const bf16* hw = canon + C_HWS;
  __shared__ bf16 wt[64 * 264];   // W^T [e][f], row stride 264
  int bid = blockIdx.x, tid = threadIdx.x;
  int b = bid >> 5, s = (bid >> 3) & 3, rc = bid & 7;
  for (int idx = tid; idx < HA_ * E_; idx += 256) {
    int f = idx >> 6, e = idx & 63;
    wt[e * 264 + f] = hw[(size_t)s * HA_ * E_ + idx];
  }
  __syncthreads();
  bool isf32 = (*flag != 0);
  int lane = tid & 63, wave = tid >> 6, quad = lane >> 4, r = lane & 15;
  int row0 = rc * 64 + wave * 16;
  const size_t xbase = (size_t)(b * S_ + s) * L_ * HA_;
  bf16x8 af[8];
#pragma unroll
  for (int kc = 0; kc < 8; ++kc)
    af[kc] = *(const bf16x8*)&outs[xbase + (size_t)(row0 + r) * HA_ + kc * 32 + quad * 8];
#pragma unroll
  for (int nt = 0; nt < 4; ++nt) {
    f32x4 acc = {0.f,0.f,0.f,0.f};
#pragma unroll
    for (int kc = 0; kc < 8; ++kc) {
      bf16x8 bfr = *(const bf16x8*)&wt[(nt * 16 + r) * 264 + kc * 32 + quad * 8];
      acc = __builtin_amdgcn_mfma_f32_16x16x32_bf16(af[kc], bfr, acc, 0,0,0);
    }
#pragma unroll
    for (int reg = 0; reg < 4; ++reg) {
      int row = row0 + quad * 4 + reg;
      int e = nt * 16 + r;
      size_t oidx = ((size_t)(b * S_ + s) * L_ + row) * E_ + e;
      if (isf32) ((float*)out)[oidx] = acc[reg];
      else       ((bf16*)out)[oidx]  = (bf16)acc[reg];
    }
  }
}

// ---------------------------------------------------------------------------
// Kernel 5: constant head projection. grid 16 = (b,c), 64 threads (e).
// ---------------------------------------------------------------------------
__global__ __launch_bounds__(64) void hproj_c_kernel(
    const float* __restrict__ outc, const bf16* __restrict__ canon,
    void* __restrict__ out, const int* __restrict__ flag)
{
  const bf16* hwc = canon + C_HWC;
  int bid = blockIdx.x, e = threadIdx.x;
  int b = bid >> 2, c = bid & 3;
  bool isf32 = (*flag != 0);
  float acc = 0.f;
#pragma unroll 4
  for (int f = 0; f < HA_; ++f)
    acc += outc[(size_t)(b * C_ + c) * HA_ + f] * (float)hwc[((size_t)c * HA_ + f) * E_ + e];
  size_t oidx = (size_t)B_ * S_ * L_ * E_ + (size_t)(b * C_ + c) * E_ + e;
  if (isf32) ((float*)out)[oidx] = acc;
  else       ((bf16*)out)[oidx]  = (bf16)acc;
}

extern "C" void kernel_launch(void* const* d_in, const int* in_sizes, int n_in,
                              void* d_out, int out_size, void* d_ws, size_t ws_size,
                              hipStream_t stream) {
  char* ws = (char*)d_ws;
  bf16* qs    = (bf16*)(ws + OFF_QS);
  bf16* kall  = (bf16*)(ws + OFF_KALL);
  bf16* vt    = (bf16*)(ws + OFF_VT);
  bf16* outs  = (bf16*)(ws + OFF_OUTS);
  float* outc = (float*)(ws + OFF_OUTC);
  bf16* canon = (bf16*)(ws + OFF_CANON);
  int* flag   = (int*)(ws + OFF_FLAG);
  const int* maskp = (const int*)d_in[14];

  ConvArgs ca;
  const int offs[13] = {C_XQ, C_XK, C_XV, C_QC, C_KC, C_VC, C_WQ, C_WK, C_WV,
                        C_WQC, C_WKC, C_WVC, C_HWS};
  for (int i = 0; i < 13; ++i) {
    ca.src[i] = d_in[i];
    ca.n[i]   = in_sizes[i];
    ca.off[i] = offs[i];
  }
  // append head_w_con as segment via a second pass: fold into slot 12..
  // (13 segments only covers d_in[0..12]; handle d_in[13] by extending)
  // -- we instead run conv twice is wasteful; extend struct usage below.

  detect_kernel<<<1, 256, 0, stream>>>((const unsigned short*)d_in[0], flag);
  conv_kernel<<<512, 256, 0, stream>>>(ca, canon, flag);
  // convert head_w_con separately via a tiny second conv with 1 segment
  ConvArgs cb;
  for (int i = 0; i < 13; ++i) { cb.src[i] = d_in[13]; cb.n[i] = 0; cb.off[i] = C_HWC; }
  cb.n[0] = in_sizes[13];
  conv_kernel<<<64, 256, 0, stream>>>(cb, canon, flag);

  proj_kernel<<<256, 256, 0, stream>>>(canon, qs, kall, vt);
  attn_kernel<<<512, 256, 0, stream>>>(qs, kall, vt, maskp, outs);
  cattn_kernel<<<128, 64, 0, stream>>>(canon, kall, vt, outc);
  hproj_s_kernel<<<128, 256, 0, stream>>>(outs, canon, d_out, flag);
  hproj_c_kernel<<<16, 64, 0, stream>>>(outc, canon, d_out, flag);
}

// Round 3
// 220.347 us; speedup vs baseline: 1.5828x; 1.5828x over previous
//
#include <hip/hip_runtime.h>
#include <hip/hip_bf16.h>

#define B_ 4
#define S_ 4
#define C_ 4
#define L_ 512
#define E_ 64
#define A_ 32
#define H_ 8
#define HA_ 256      // H_*A_
#define KREAL 2052   // S_*L_ + C_
#define KP 2112      // padded to 33*64
#define NKT 33
#define SCALE 0.17677669529663687f  // 1/sqrt(32)
#define NEGINF (-__builtin_inff())

using bf16  = __bf16;
using bf16x8 = __attribute__((ext_vector_type(8))) __bf16;
using f32x4  = __attribute__((ext_vector_type(4))) float;

// workspace layout (byte offsets)
#define OFF_QS    0ull            // bf16 [B][S][H][L][A]  (pre-scaled by 1/sqrt(A))
#define OFF_KALL  4194304ull      // bf16 [B][H][KP][A]
#define OFF_VT    8519680ull      // bf16 [B][H][A][KP]
#define OFF_OUTS  12845056ull     // bf16 [B][S][L][HA]
#define OFF_OUTC  17039360ull     // f32  [B][C][HA]
#define OFF_CANON 17055744ull     // bf16 canonical inputs
#define OFF_FLAG  21256192ull     // int  is_f32 flag
// total ~21.3 MB

// canonical pool element offsets
#define C_XQ   0
#define C_XK   524288
#define C_XV   1048576
#define C_QC   1572864
#define C_KC   1573888
#define C_VC   1574912
#define C_WQ   1575936
#define C_WK   1641472
#define C_WV   1707008
#define C_WQC  1772544
#define C_WKC  1838080
#define C_WVC  1903616
#define C_HWS  1969152
#define C_HWC  2034688

// ---------------------------------------------------------------------------
// Kernel 0a: dtype detection (low halfwords of input 0: f32 mantissa noise vs
// sane bf16 exponents).
// ---------------------------------------------------------------------------
__global__ __launch_bounds__(256) void detect_kernel(
    const unsigned short* __restrict__ x, int* __restrict__ flag)
{
  __shared__ int cnt;
  if (threadIdx.x == 0) cnt = 0;
  __syncthreads();
  int weird = 0;
  for (int i = threadIdx.x; i < 4096; i += 256) {
    unsigned short h = x[2 * i];
    int e = (h >> 7) & 0xFF;
    if (e == 0xFF || e < 0x60 || e > 0x9F) weird++;
  }
  atomicAdd(&cnt, weird);
  __syncthreads();
  if (threadIdx.x == 0) *flag = (cnt > 1024) ? 1 : 0;
}

// ---------------------------------------------------------------------------
// Kernel 0b: canonicalize all 14 float inputs to bf16 in ws (single launch).
// ---------------------------------------------------------------------------
struct ConvArgs {
  const void* src[14];
  int n[14];
  int off[14];
};

__global__ __launch_bounds__(256) void conv_kernel(
    ConvArgs args, bf16* __restrict__ dst, const int* __restrict__ flag)
{
  bool isf32 = (*flag != 0);
  int stride = gridDim.x * blockDim.x;
  int t0 = blockIdx.x * blockDim.x + threadIdx.x;
#pragma unroll 1
  for (int seg = 0; seg < 14; ++seg) {
    int n = args.n[seg];
    bf16* d = dst + args.off[seg];
    if (isf32) {
      const float* s = (const float*)args.src[seg];
      for (int i = t0; i < n; i += stride) d[i] = (bf16)s[i];
    } else {
      const bf16* s = (const bf16*)args.src[seg];
      for (int i = t0; i < n; i += stride) d[i] = s[i];
    }
  }
}

// ---------------------------------------------------------------------------
// Kernel 1: QKV projections (MFMA). qs is pre-scaled by 1/sqrt(A).
// ---------------------------------------------------------------------------
__global__ __launch_bounds__(256) void proj_kernel(
    const bf16* __restrict__ canon,
    bf16* __restrict__ qs, bf16* __restrict__ kall, bf16* __restrict__ vt)
{
  const bf16* xq    = canon + C_XQ;
  const bf16* xk    = canon + C_XK;
  const bf16* xv    = canon + C_XV;
  const bf16* kc_in = canon + C_KC;
  const bf16* vc_in = canon + C_VC;
  const bf16* wq    = canon + C_WQ;
  const bf16* wk    = canon + C_WK;
  const bf16* wv    = canon + C_WV;
  const bf16* wkc   = canon + C_WKC;
  const bf16* wvc   = canon + C_WVC;
  int bid = blockIdx.x;
  int tid = threadIdx.x;
  if (bid < 128) {
    int b = bid >> 5, s = (bid >> 3) & 3, h = bid & 7;
    __shared__ bf16 wt[3 * 32 * 72];
    for (int idx = tid; idx < 2048; idx += 256) {
      int e = idx >> 5, a = idx & 31;
      size_t src = ((size_t)(s * H_ + h) * E_ + e) * A_ + a;
      wt[0 * 2304 + a * 72 + e] = wq[src];
      wt[1 * 2304 + a * 72 + e] = wk[src];
      wt[2 * 2304 + a * 72 + e] = wv[src];
    }
    __syncthreads();
    int lane = tid & 63, wave = tid >> 6;
    int quad = lane >> 4, r = lane & 15;
    bf16x8 bq[2][2], bk[2][2], bv[2][2];
#pragma unroll
    for (int kc = 0; kc < 2; ++kc)
#pragma unroll
      for (int nt = 0; nt < 2; ++nt) {
        int off = (nt * 16 + r) * 72 + kc * 32 + quad * 8;
        bq[kc][nt] = *(const bf16x8*)&wt[off];
        bk[kc][nt] = *(const bf16x8*)&wt[2304 + off];
        bv[kc][nt] = *(const bf16x8*)&wt[4608 + off];
      }
    const size_t xbase = (size_t)(b * S_ + s) * L_ * E_;
    const size_t qsb   = (size_t)((b * S_ + s) * H_ + h) * L_ * A_;
    const size_t kab   = (size_t)(b * H_ + h) * KP * A_;
    const size_t vtb   = (size_t)(b * H_ + h) * A_ * KP;
#pragma unroll 1
    for (int i = 0; i < 8; ++i) {
      int row0 = (wave * 8 + i) * 16;
      size_t rowoff = xbase + (size_t)(row0 + r) * E_ + quad * 8;
      bf16x8 aq0 = *(const bf16x8*)&xq[rowoff];
      bf16x8 aq1 = *(const bf16x8*)&xq[rowoff + 32];
      bf16x8 ak0 = *(const bf16x8*)&xk[rowoff];
      bf16x8 ak1 = *(const bf16x8*)&xk[rowoff + 32];
      bf16x8 av0 = *(const bf16x8*)&xv[rowoff];
      bf16x8 av1 = *(const bf16x8*)&xv[rowoff + 32];
#pragma unroll
      for (int nt = 0; nt < 2; ++nt) {
        f32x4 accq = {0.f,0.f,0.f,0.f}, acck = {0.f,0.f,0.f,0.f}, accv = {0.f,0.f,0.f,0.f};
        accq = __builtin_amdgcn_mfma_f32_16x16x32_bf16(aq0, bq[0][nt], accq, 0,0,0);
        accq = __builtin_amdgcn_mfma_f32_16x16x32_bf16(aq1, bq[1][nt], accq, 0,0,0);
        acck = __builtin_amdgcn_mfma_f32_16x16x32_bf16(ak0, bk[0][nt], acck, 0,0,0);
        acck = __builtin_amdgcn_mfma_f32_16x16x32_bf16(ak1, bk[1][nt], acck, 0,0,0);
        accv = __builtin_amdgcn_mfma_f32_16x16x32_bf16(av0, bv[0][nt], accv, 0,0,0);
        accv = __builtin_amdgcn_mfma_f32_16x16x32_bf16(av1, bv[1][nt], accv, 0,0,0);
#pragma unroll
        for (int reg = 0; reg < 4; ++reg) {
          int l = row0 + quad * 4 + reg;
          int a = nt * 16 + r;
          qs[qsb + (size_t)l * A_ + a]              = (bf16)(accq[reg] * SCALE);
          kall[kab + (size_t)(s * L_ + l) * A_ + a] = (bf16)acck[reg];
          vt[vtb + (size_t)a * KP + s * L_ + l]     = (bf16)accv[reg];
        }
      }
    }
  } else {
    int cid = bid - 128;
    int b = cid >> 5, c = (cid >> 3) & 3, h = cid & 7;
    if (tid < 32) {
      int a = tid;
      float kacc = 0.f, vacc = 0.f;
#pragma unroll 8
      for (int e = 0; e < E_; ++e) {
        float xke = (float)kc_in[(b * C_ + c) * E_ + e];
        float xve = (float)vc_in[(b * C_ + c) * E_ + e];
        float wke = (float)wkc[((size_t)(c * H_ + h) * E_ + e) * A_ + a];
        float wve = (float)wvc[((size_t)(c * H_ + h) * E_ + e) * A_ + a];
        kacc += xke * wke;
        vacc += xve * wve;
      }
      kall[((size_t)(b * H_ + h) * KP + (S_ * L_ + c)) * A_ + a] = (bf16)kacc;
      vt[((size_t)(b * H_ + h) * A_ + a) * KP + (S_ * L_ + c)]   = (bf16)vacc;
    }
    if (c == 0) {  // zero pad keys 2052..2111
      for (int idx = tid; idx < 60 * 32; idx += 256) {
        int k = KREAL + (idx >> 5), a = idx & 31;
        kall[((size_t)(b * H_ + h) * KP + k) * A_ + a] = (bf16)0.f;
        vt[((size_t)(b * H_ + h) * A_ + a) * KP + k]   = (bf16)0.f;
      }
    }
  }
}

// ---------------------------------------------------------------------------
// Kernel 2: flash attention, transposed scores + causal tile skipping.
// grid 1024 = (b,s,h,qt of 64 rows); 4 waves x 16 rows.
// ---------------------------------------------------------------------------
__global__ __launch_bounds__(256) void attn_kernel(
    const bf16* __restrict__ qs, const bf16* __restrict__ kall, const bf16* __restrict__ vt,
    const int* __restrict__ maskp, bf16* __restrict__ outs)
{
  __shared__ bf16 kt_lds[64 * 40];     // K tile  [key][a], stride 40
  __shared__ bf16 vt_lds[32 * 72];     // V^T tile [a][key], stride 72
  __shared__ bf16 p_lds[4 * 16 * 72];  // per-wave P tile [qrow][key], stride 72
  int bid = blockIdx.x, tid = threadIdx.x;
  int qt = bid & 7, h = (bid >> 3) & 7, s = (bid >> 6) & 3, b = (bid >> 8) & 3;
  int lane = tid & 63, wave = tid >> 6, quad = lane >> 4, r = lane & 15;
  bool causal = (*maskp != 0);
  int wrow = qt * 64 + wave * 16;      // wave's first query row
  int lrow = wrow + r;                 // this lane's softmax row
  int blockmax = qt * 64 + 63;

  const size_t qsb = (size_t)((b * S_ + s) * H_ + h) * L_ * A_;
  // Q fragment, used as MFMA *B*-operand: B[k=a][n=qrow]
  bf16x8 aq = *(const bf16x8*)&qs[qsb + (size_t)(wrow + r) * A_ + quad * 8];

  f32x4 o[2];
  { f32x4 z = {0.f,0.f,0.f,0.f}; o[0] = z; o[1] = z; }
  float m_run = -1e30f, l_run = 0.f;

  const size_t kbase = (size_t)(b * H_ + h) * KP * A_;
  const size_t vbase = (size_t)(b * H_ + h) * A_ * KP;
  const int pbase = wave * 16 * 72;

#pragma unroll 1
  for (int kt = 0; kt < NKT; ++kt) {
    int kmod = (kt & 7) * 64;          // key time within 512-block (seq tiles)
    // block-uniform skip: no row in this block sees this tile
    if (causal && kt < 32 && kmod > blockmax) continue;
    __syncthreads();
    {
      int krow = tid >> 2, c4 = tid & 3;
      *(bf16x8*)&kt_lds[krow * 40 + c4 * 8] =
          *(const bf16x8*)&kall[kbase + (size_t)(kt * 64 + krow) * A_ + c4 * 8];
      int a8 = tid >> 3, c8 = tid & 7;
      *(bf16x8*)&vt_lds[a8 * 72 + c8 * 8] =
          *(const bf16x8*)&vt[vbase + (size_t)a8 * KP + kt * 64 + c8 * 8];
    }
    __syncthreads();
    // wave-level skip: this wave's 16 rows all precede the tile
    if (causal && kt < 32 && kmod >= wrow + 16) continue;
    bool fullv = (kt < 32) && (!causal || kmod + 63 <= wrow);

    // scores transposed: D[key_local][qrow], lane holds 16 keys of row lrow
    f32x4 sf[4];
#pragma unroll
    for (int kg = 0; kg < 4; ++kg) {
      bf16x8 ka = *(const bf16x8*)&kt_lds[(kg * 16 + r) * 40 + quad * 8];
      f32x4 z = {0.f,0.f,0.f,0.f};
      sf[kg] = __builtin_amdgcn_mfma_f32_16x16x32_bf16(ka, aq, z, 0,0,0);
    }
    if (!fullv) {
      int thresh = (kt < 32) ? (lrow - kmod) : 3;  // visible iff local <= thresh
#pragma unroll
      for (int kg = 0; kg < 4; ++kg)
#pragma unroll
        for (int reg = 0; reg < 4; ++reg)
          if (kg * 16 + quad * 4 + reg > thresh) sf[kg][reg] = NEGINF;
    }
    // row max: in-lane 16 + cross-quad
    float t01 = fmaxf(fmaxf(sf[0][0], sf[0][1]), fmaxf(sf[0][2], sf[0][3]));
    float t23 = fmaxf(fmaxf(sf[1][0], sf[1][1]), fmaxf(sf[1][2], sf[1][3]));
    float t45 = fmaxf(fmaxf(sf[2][0], sf[2][1]), fmaxf(sf[2][2], sf[2][3]));
    float t67 = fmaxf(fmaxf(sf[3][0], sf[3][1]), fmaxf(sf[3][2], sf[3][3]));
    float tmax = fmaxf(fmaxf(t01, t23), fmaxf(t45, t67));
    tmax = fmaxf(tmax, __shfl_xor(tmax, 16));
    tmax = fmaxf(tmax, __shfl_xor(tmax, 32));
    float mnew = fmaxf(m_run, tmax);
    float alpha = __expf(m_run - mnew);
    m_run = mnew;
    // p = exp(s - mnew), pack 4 consecutive keys -> one b64 LDS write
    float psum = 0.f;
#pragma unroll
    for (int kg = 0; kg < 4; ++kg) {
      float p0 = __expf(sf[kg][0] - mnew);
      float p1 = __expf(sf[kg][1] - mnew);
      float p2 = __expf(sf[kg][2] - mnew);
      float p3 = __expf(sf[kg][3] - mnew);
      psum += (p0 + p1) + (p2 + p3);
      union { bf16 hh[4]; uint2 u2; } pk;
      pk.hh[0] = (bf16)p0; pk.hh[1] = (bf16)p1; pk.hh[2] = (bf16)p2; pk.hh[3] = (bf16)p3;
      *(uint2*)&p_lds[pbase + r * 72 + kg * 16 + quad * 4] = pk.u2;
    }
    psum += __shfl_xor(psum, 16);
    psum += __shfl_xor(psum, 32);
    l_run = l_run * alpha + psum;
    // rescale O (C-layout rows quad*4+reg): broadcast alpha from owning lane
#pragma unroll
    for (int reg = 0; reg < 4; ++reg) {
      float ao = __shfl(alpha, (lane & 48) | (quad * 4 + reg));
      o[0][reg] *= ao;
      o[1][reg] *= ao;
    }
    // PV
#pragma unroll
    for (int kc2 = 0; kc2 < 2; ++kc2) {
      bf16x8 ap = *(const bf16x8*)&p_lds[pbase + r * 72 + kc2 * 32 + quad * 8];
#pragma unroll
      for (int nt = 0; nt < 2; ++nt) {
        bf16x8 bv = *(const bf16x8*)&vt_lds[(nt * 16 + r) * 72 + kc2 * 32 + quad * 8];
        o[nt] = __builtin_amdgcn_mfma_f32_16x16x32_bf16(ap, bv, o[nt], 0,0,0);
      }
    }
  }
  // epilogue: broadcast l to C-layout rows, divide, store
  const size_t obase = (size_t)(b * S_ + s) * L_ * HA_;
#pragma unroll
  for (int reg = 0; reg < 4; ++reg) {
    float lo = __shfl(l_run, (lane & 48) | (quad * 4 + reg));
    int orow = wrow + quad * 4 + reg;
#pragma unroll
    for (int nt = 0; nt < 2; ++nt) {
      int f = h * A_ + nt * 16 + r;
      outs[obase + (size_t)orow * HA_ + f] = (bf16)(o[nt][reg] / lo);
    }
  }
}

// ---------------------------------------------------------------------------
// Kernel 3: constant-query attention. grid 128 = (b,c,h), 256 threads.
// ---------------------------------------------------------------------------
__global__ __launch_bounds__(256) void cattn_kernel(
    const bf16* __restrict__ canon,
    const bf16* __restrict__ kall, const bf16* __restrict__ vt,
    float* __restrict__ outc)
{
  const bf16* qc  = canon + C_QC;
  const bf16* wqc = canon + C_WQC;
  __shared__ float qsh[32];
  __shared__ float parr[KP];        // scores then p; pads zeroed
  __shared__ float red[8];
  __shared__ float opart[32][9];
  int bid = blockIdx.x, tid = threadIdx.x;
  int b = bid >> 5, c = (bid >> 3) & 3, h = bid & 7;
  int lane = tid & 63, wave = tid >> 6;
  if (tid < 32) {
    float acc = 0.f;
#pragma unroll 8
    for (int e = 0; e < E_; ++e)
      acc += (float)qc[(b * C_ + c) * E_ + e] *
             (float)wqc[((size_t)(c * H_ + h) * E_ + e) * A_ + tid];
    qsh[tid] = acc * SCALE;
  }
  if (tid >= 192 && tid < 192 + (KP - KREAL)) parr[KREAL + tid - 192] = 0.f;
  __syncthreads();
  const size_t kbase = (size_t)(b * H_ + h) * KP * A_;
  float lmax = -1e30f;
#pragma unroll 1
  for (int j = 0; j < 9; ++j) {
    int k = tid + j * 256;
    if (k < KREAL) {
      bf16x8 k0 = *(const bf16x8*)&kall[kbase + (size_t)k * A_ + 0];
      bf16x8 k1 = *(const bf16x8*)&kall[kbase + (size_t)k * A_ + 8];
      bf16x8 k2 = *(const bf16x8*)&kall[kbase + (size_t)k * A_ + 16];
      bf16x8 k3 = *(const bf16x8*)&kall[kbase + (size_t)k * A_ + 24];
      float d = 0.f;
#pragma unroll
      for (int i = 0; i < 8; ++i) {
        d += qsh[i]      * (float)k0[i];
        d += qsh[8 + i]  * (float)k1[i];
        d += qsh[16 + i] * (float)k2[i];
        d += qsh[24 + i] * (float)k3[i];
      }
      parr[k] = d;
      lmax = fmaxf(lmax, d);
    }
  }
#pragma unroll
  for (int dlt = 1; dlt < 64; dlt <<= 1) lmax = fmaxf(lmax, __shfl_xor(lmax, dlt));
  if (lane == 0) red[wave] = lmax;
  __syncthreads();
  float bmax = fmaxf(fmaxf(red[0], red[1]), fmaxf(red[2], red[3]));
  float lsum = 0.f;
#pragma unroll 1
  for (int j = 0; j < 9; ++j) {
    int k = tid + j * 256;
    if (k < KREAL) {
      float p = __expf(parr[k] - bmax);
      parr[k] = p;
      lsum += p;
    }
  }
#pragma unroll
  for (int dlt = 1; dlt < 64; dlt <<= 1) lsum += __shfl_xor(lsum, dlt);
  if (lane == 0) red[4 + wave] = lsum;
  __syncthreads();
  float bsum = (red[4] + red[5]) + (red[6] + red[7]);
  int a = tid >> 3, ch = tid & 7;
  const size_t vbase = (size_t)(b * H_ + h) * A_ * KP + (size_t)a * KP;
  float acc = 0.f;
#pragma unroll 1
  for (int j = 0; j < 33; ++j) {
    int kb = ch * 8 + j * 64;
    bf16x8 vv = *(const bf16x8*)&vt[vbase + kb];
    float4 p0 = *(float4*)&parr[kb];
    float4 p1 = *(float4*)&parr[kb + 4];
    acc += p0.x * (float)vv[0] + p0.y * (float)vv[1] + p0.z * (float)vv[2] + p0.w * (float)vv[3];
    acc += p1.x * (float)vv[4] + p1.y * (float)vv[5] + p1.z * (float)vv[6] + p1.w * (float)vv[7];
  }
  opart[a][ch] = acc;
  __syncthreads();
  if (tid < 32) {
    float t = 0.f;
#pragma unroll
    for (int i = 0; i < 8; ++i) t += opart[tid][i];
    outc[(size_t)(b * C_ + c) * HA_ + h * A_ + tid] = t / bsum;
  }
}

// ---------------------------------------------------------------------------
// Kernel 4: seq head projection via MFMA. grid 128 = (b,s,rowchunk of 64).
// ---------------------------------------------------------------------------
__global__ __launch_bounds__(256) void hproj_s_kernel(
    const bf16* __restrict__ outs, const bf16* __restrict__ canon,
    void* __restrict__ out, const int* __restrict__ flag)
{
  const bf16* hw = canon + C_HWS;
  __shared__ bf16 wt[64 * 264];
  int bid = blockIdx.x, tid = threadIdx.x;
  int b = bid >> 5, s = (bid >> 3) & 3, rc = bid & 7;
  for (int idx = tid; idx < HA_ * E_; idx += 256) {
    int f = idx >> 6, e = idx & 63;
    wt[e * 264 + f] = hw[(size_t)s * HA_ * E_ + idx];
  }
  __syncthreads();
  bool isf32 = (*flag != 0);
  int lane = tid & 63, wave = tid >> 6, quad = lane >> 4, r = lane & 15;
  int row0 = rc * 64 + wave * 16;
  const size_t xbase = (size_t)(b * S_ + s) * L_ * HA_;
  bf16x8 af[8];
#pragma unroll
  for (int kc = 0; kc < 8; ++kc)
    af[kc] = *(const bf16x8*)&outs[xbase + (size_t)(row0 + r) * HA_ + kc * 32 + quad * 8];
#pragma unroll
  for (int nt = 0; nt < 4; ++nt) {
    f32x4 acc = {0.f,0.f,0.f,0.f};
#pragma unroll
    for (int kc = 0; kc < 8; ++kc) {
      bf16x8 bfr = *(const bf16x8*)&wt[(nt * 16 + r) * 264 + kc * 32 + quad * 8];
      acc = __builtin_amdgcn_mfma_f32_16x16x32_bf16(af[kc], bfr, acc, 0,0,0);
    }
#pragma unroll
    for (int reg = 0; reg < 4; ++reg) {
      int row = row0 + quad * 4 + reg;
      int e = nt * 16 + r;
      size_t oidx = ((size_t)(b * S_ + s) * L_ + row) * E_ + e;
      if (isf32) ((float*)out)[oidx] = acc[reg];
      else       ((bf16*)out)[oidx]  = (bf16)acc[reg];
    }
  }
}

// ---------------------------------------------------------------------------
// Kernel 5: constant head projection. grid 16 = (b,c), 64 threads (e).
// ---------------------------------------------------------------------------
__global__ __launch_bounds__(64) void hproj_c_kernel(
    const float* __restrict__ outc, const bf16* __restrict__ canon,
    void* __restrict__ out, const int* __restrict__ flag)
{
  const bf16* hwc = canon + C_HWC;
  int bid = blockIdx.x, e = threadIdx.x;
  int b = bid >> 2, c = bid & 3;
  bool isf32 = (*flag != 0);
  float acc = 0.f;
#pragma unroll 4
  for (int f = 0; f < HA_; ++f)
    acc += outc[(size_t)(b * C_ + c) * HA_ + f] * (float)hwc[((size_t)c * HA_ + f) * E_ + e];
  size_t oidx = (size_t)B_ * S_ * L_ * E_ + (size_t)(b * C_ + c) * E_ + e;
  if (isf32) ((float*)out)[oidx] = acc;
  else       ((bf16*)out)[oidx]  = (bf16)acc;
}

extern "C" void kernel_launch(void* const* d_in, const int* in_sizes, int n_in,
                              void* d_out, int out_size, void* d_ws, size_t ws_size,
                              hipStream_t stream) {
  char* ws = (char*)d_ws;
  bf16* qs    = (bf16*)(ws + OFF_QS);
  bf16* kall  = (bf16*)(ws + OFF_KALL);
  bf16* vt    = (bf16*)(ws + OFF_VT);
  bf16* outs  = (bf16*)(ws + OFF_OUTS);
  float* outc = (float*)(ws + OFF_OUTC);
  bf16* canon = (bf16*)(ws + OFF_CANON);
  int* flag   = (int*)(ws + OFF_FLAG);
  const int* maskp = (const int*)d_in[14];

  ConvArgs ca;
  const int offs[14] = {C_XQ, C_XK, C_XV, C_QC, C_KC, C_VC, C_WQ, C_WK, C_WV,
                        C_WQC, C_WKC, C_WVC, C_HWS, C_HWC};
  for (int i = 0; i < 14; ++i) {
    ca.src[i] = d_in[i];
    ca.n[i]   = in_sizes[i];
    ca.off[i] = offs[i];
  }

  detect_kernel<<<1, 256, 0, stream>>>((const unsigned short*)d_in[0], flag);
  conv_kernel<<<512, 256, 0, stream>>>(ca, canon, flag);
  proj_kernel<<<256, 256, 0, stream>>>(canon, qs, kall, vt);
  attn_kernel<<<1024, 256, 0, stream>>>(qs, kall, vt, maskp, outs);
  cattn_kernel<<<128, 256, 0, stream>>>(canon, kall, vt, outc);
  hproj_s_kernel<<<128, 256, 0, stream>>>(outs, canon, d_out, flag);
  hproj_c_kernel<<<16, 64, 0, stream>>>(outc, canon, d_out, flag);
}